// Round 5
// baseline (227.376 us; speedup 1.0000x reference)
//
#include <hip/hip_runtime.h>

typedef short bf16x8 __attribute__((ext_vector_type(8)));
typedef float f32x4 __attribute__((ext_vector_type(4)));

#define MFMA16(a, b, c) __builtin_amdgcn_mfma_f32_16x16x32_bf16(a, b, c, 0, 0, 0)

constexpr int Bn = 4, Sn = 4096, En = 1024, Hn = 128;

__device__ inline unsigned short f2bf(float f) {
    unsigned int u = __builtin_bit_cast(unsigned int, f);
    u += 0x7fff + ((u >> 16) & 1);   // RTN
    return (unsigned short)(u >> 16);
}

// pack 2 floats -> 2 bf16 (round-to-nearest-away): 2 adds + 1 v_perm
__device__ inline unsigned int pk2(float a, float b) {
    unsigned int ua = __builtin_bit_cast(unsigned int, a) + 0x8000u;
    unsigned int ub = __builtin_bit_cast(unsigned int, b) + 0x8000u;
    return __builtin_amdgcn_perm(ub, ua, 0x07060302u);  // {ub.hi16, ua.hi16}
}

// ---------------- prep: W fp32 -> bf16, order [q,k,v][h][E] ----------------
// grid 96 x 256: 32 blocks per W, thread does 4 float4 (16 elems)
__global__ __launch_bounds__(256) void prep_kernel(
    const float* __restrict__ Wk, const float* __restrict__ Wq, const float* __restrict__ Wv,
    unsigned short* __restrict__ wb)
{
    int gy = blockIdx.x >> 5;
    const float* src = (gy == 0) ? Wq : (gy == 1) ? Wk : Wv;
    unsigned short* dst = wb + (size_t)gy * Hn * En;
    int t = (blockIdx.x & 31) * 256 + threadIdx.x;     // 0..8191
    const float4* s4 = (const float4*)src;
    for (int i = 0; i < 4; ++i) {
        float4 v = s4[(size_t)t * 4 + i];
        uint2 w2 = { pk2(v.x, v.y), pk2(v.z, v.w) };
        *(uint2*)&dst[(size_t)t * 16 + i * 4] = w2;
    }
}

// ---------------- fused QKV projection ----------------
// Block: 32 x-rows, all 128 h, all 3 projections (x read ONCE from HBM).
// 4 waves: wave w owns h in [w*32, w*32+32). BK=64, 16 k-steps.
// x: fp32 -> bf16 into double-buffered LDS (A-frag for q/k, B-frag for vT).
// W: bf16 fragments loaded straight to registers (row = wn+j*16+l15 -> 64B sectors, L2-hot).
// q/k: C = x W^T (m=s-row). vT: C = Wv x^T (m=h) -> epilogue writes [b][h][s].
__global__ __launch_bounds__(256, 2) void proj_kernel(
    const float* __restrict__ x, const unsigned short* __restrict__ wb,
    unsigned short* __restrict__ qb, unsigned short* __restrict__ kb,
    unsigned short* __restrict__ vbT)
{
    __shared__ unsigned short xs[2][32][68];

    const int m0 = blockIdx.x * 32;
    const int tid = threadIdx.x;
    const int lane = tid & 63, wave = tid >> 6;
    const int l15 = lane & 15, quad = lane >> 4;
    const int wn = wave * 32;                      // h base for this wave

    f32x4 acc[3][2][2] = {};                       // [gy][i][j]

    // x fp32 prefetch: 32 rows x 16 float4 = 512 chunks / 256 thr = 2 each
    float4 xp[2];
    for (int p = 0; p < 2; ++p) {
        int i = p * 256 + tid, row = i >> 4, c4 = (i & 15) * 4;
        xp[p] = *(const float4*)&x[(size_t)(m0 + row) * En + c4];
    }

    // per-lane W row base: row = wn + l15 (j adds 16 rows, gy adds Hn rows)
    const unsigned short* wrow = wb + (size_t)(wn + l15) * En + quad * 8;

    for (int kc = 0; kc < En / 64; ++kc) {
        const int c = kc & 1;
        const int k0 = kc * 64;

        // issue W frag loads for this kc (consumed after barrier; covered by stage+prefetch)
        bf16x8 wf[3][2][2];
        for (int gy = 0; gy < 3; ++gy)
            for (int j = 0; j < 2; ++j)
                for (int kk = 0; kk < 2; ++kk)
                    wf[gy][j][kk] = *(const bf16x8*)&wrow[(size_t)gy * Hn * En + (size_t)j * 16 * En + k0 + kk * 32];

        // stage x tile (bf16) into xs[c]
        for (int p = 0; p < 2; ++p) {
            int i = p * 256 + tid, row = i >> 4, cc = (i & 15) * 4;
            uint2 w2 = { pk2(xp[p].x, xp[p].y), pk2(xp[p].z, xp[p].w) };
            *(uint2*)&xs[c][row][cc] = w2;
        }
        __syncthreads();

        // prefetch next x k-slice
        {
            int kn = (kc + 1 < En / 64) ? kc + 1 : kc;
            for (int p = 0; p < 2; ++p) {
                int i = p * 256 + tid, row = i >> 4, c4 = (i & 15) * 4;
                xp[p] = *(const float4*)&x[(size_t)(m0 + row) * En + kn * 64 + c4];
            }
        }

        // x fragments (shared by all 3 projections)
        bf16x8 xf[2][2];
        for (int i = 0; i < 2; ++i)
            for (int kk = 0; kk < 2; ++kk)
                xf[i][kk] = *(const bf16x8*)&xs[c][i * 16 + l15][kk * 32 + quad * 8];

        for (int kk = 0; kk < 2; ++kk)
            for (int i = 0; i < 2; ++i)
                for (int j = 0; j < 2; ++j) {
                    acc[0][i][j] = MFMA16(xf[i][kk], wf[0][j][kk], acc[0][i][j]);  // q
                    acc[1][i][j] = MFMA16(xf[i][kk], wf[1][j][kk], acc[1][i][j]);  // k
                    acc[2][i][j] = MFMA16(wf[2][j][kk], xf[i][kk], acc[2][i][j]);  // v^T
                }
        // no second barrier: next iter writes xs[c^1]; xs[c] rewritten only after
        // every wave passes the NEXT barrier (which requires finishing these reads)
    }

    // epilogue
    for (int gy = 0; gy < 2; ++gy) {
        unsigned short* ob = (gy == 0) ? qb : kb;
        for (int i = 0; i < 2; ++i) {
            int rowb = m0 + i * 16 + quad * 4;
            for (int j = 0; j < 2; ++j) {
                int col = wn + j * 16 + l15;
                for (int r = 0; r < 4; ++r)
                    ob[(size_t)(rowb + r) * Hn + col] = f2bf(acc[gy][i][j][r]);
            }
        }
    }
    for (int j = 0; j < 2; ++j) {
        int hb = wn + j * 16 + quad * 4;
        for (int i = 0; i < 2; ++i) {
            int sp = m0 + i * 16 + l15;
            int bb = sp >> 12, ss = sp & 4095;
            for (int r = 0; r < 4; ++r)
                vbT[((size_t)(bb * 128 + hb + r)) * Sn + ss] = f2bf(acc[2][i][j][r]);
        }
    }
}

// ---------------- flash causal attention, in-block 2-way K-split ----------------
// (unchanged from R4)
__global__ __launch_bounds__(256, 2) void attn_kernel(
    const unsigned short* __restrict__ qb, const unsigned short* __restrict__ kb,
    const unsigned short* __restrict__ vbT, float* __restrict__ out)
{
    __shared__ unsigned short ks[2][64][132];
    __shared__ unsigned short vt[2][128][68];
    __shared__ unsigned short ps[2][32][68];

    const int b = blockIdx.y;
    const int qt = (int)gridDim.x - 1 - (int)blockIdx.x;
    const int q0 = qt * 32;
    const int tid = threadIdx.x;
    const int lane = tid & 63, wave = tid >> 6;
    const int l15 = lane & 15, quad = lane >> 4;
    const int g = wave & 1;
    const int p = wave >> 1;
    const int tpp = tid & 127;

    const unsigned short* qg = qb + (size_t)(b * Sn + q0) * Hn;
    bf16x8 qf[4];
    {
        int qrow = g * 16 + l15;
        for (int f = 0; f < 4; ++f)
            qf[f] = *(const bf16x8*)&qg[qrow * Hn + f * 32 + quad * 8];
    }

    f32x4 o[8] = {};
    float m_r = -INFINITY, l_r = 0.f;

    const float cscale = 1.44269504089f * 0.03125f;
    const int nkt = q0 / 64 + 1;
    const int ni = (nkt + 1) >> 1;

    const unsigned short* kg = kb + (size_t)b * Sn * Hn;
    const unsigned short* vg = vbT + (size_t)b * 128 * Sn;

    bf16x8 kreg[8], vreg[8];
    {
        int kt0 = p * 64;
        for (int p8 = 0; p8 < 8; ++p8) {
            int i = p8 * 128 + tpp;
            kreg[p8] = *(const bf16x8*)&kg[(size_t)(kt0 + (i >> 4)) * Hn + (i & 15) * 8];
            vreg[p8] = *(const bf16x8*)&vg[(size_t)(i >> 3) * Sn + kt0 + (i & 7) * 8];
        }
    }

    for (int it = 0; it < ni; ++it) {
        const int kt = 2 * it + p;
        const bool active = kt < nkt;
        for (int p8 = 0; p8 < 8; ++p8) {
            int i = p8 * 128 + tpp;
            *(bf16x8*)&ks[p][i >> 4][(i & 15) * 8] = kreg[p8];
            *(bf16x8*)&vt[p][i >> 3][(i & 7) * 8] = vreg[p8];
        }
        __syncthreads();
        if (kt + 2 < nkt) {
            int kt0n = (kt + 2) * 64;
            for (int p8 = 0; p8 < 8; ++p8) {
                int i = p8 * 128 + tpp;
                kreg[p8] = *(const bf16x8*)&kg[(size_t)(kt0n + (i >> 4)) * Hn + (i & 15) * 8];
                vreg[p8] = *(const bf16x8*)&vg[(size_t)(i >> 3) * Sn + kt0n + (i & 7) * 8];
            }
        }
        if (active) {
            float u[4][4];
            for (int nt = 0; nt < 4; ++nt) {
                f32x4 s = {};
                for (int kk = 0; kk < 4; ++kk) {
                    bf16x8 kf = *(const bf16x8*)&ks[p][nt * 16 + l15][kk * 32 + quad * 8];
                    s = MFMA16(kf, qf[kk], s);
                }
                for (int r = 0; r < 4; ++r) u[nt][r] = s[r] * cscale;
            }
            if (kt == nkt - 1) {
                int kt0 = kt * 64;
                int qq = q0 + g * 16 + l15;
                for (int nt = 0; nt < 4; ++nt)
                    for (int r = 0; r < 4; ++r)
                        if (kt0 + nt * 16 + quad * 4 + r > qq) u[nt][r] = -INFINITY;
            }
            float mx = -INFINITY;
            for (int nt = 0; nt < 4; ++nt)
                for (int r = 0; r < 4; ++r) mx = fmaxf(mx, u[nt][r]);
            mx = fmaxf(mx, __shfl_xor(mx, 16));
            mx = fmaxf(mx, __shfl_xor(mx, 32));
            float mn = fmaxf(m_r, mx);
            float alpha = exp2f(m_r - mn);
            m_r = mn;
            float sum = 0.f;
            for (int nt = 0; nt < 4; ++nt)
                for (int r = 0; r < 4; ++r) {
                    float pv = exp2f(u[nt][r] - mn);
                    u[nt][r] = pv;
                    sum += pv;
                }
            sum += __shfl_xor(sum, 16);
            sum += __shfl_xor(sum, 32);
            l_r = l_r * alpha + sum;

            for (int nt = 0; nt < 4; ++nt) {
                uint2 w2 = { pk2(u[nt][0], u[nt][1]), pk2(u[nt][2], u[nt][3]) };
                *(uint2*)&ps[p][g * 16 + l15][nt * 16 + quad * 4] = w2;
            }
            for (int t = 0; t < 8; ++t) o[t] *= alpha;

            for (int k2 = 0; k2 < 2; ++k2) {
                bf16x8 pf = *(const bf16x8*)&ps[p][g * 16 + l15][k2 * 32 + quad * 8];
                for (int t = 0; t < 8; ++t) {
                    bf16x8 vf = *(const bf16x8*)&vt[p][t * 16 + l15][k2 * 32 + quad * 8];
                    o[t] = MFMA16(vf, pf, o[t]);
                }
            }
        }
        __syncthreads();
    }

    float* mo = (float*)&ks[0][0][0];   // [2][128][17] f32
    float* ml = (float*)&vt[0][0][0];   // [2][{m,l}][16] f32
    if (p == 1) {
        for (int t = 0; t < 8; ++t)
            for (int r = 0; r < 4; ++r)
                mo[(size_t)(g * 128 + t * 16 + quad * 4 + r) * 17 + l15] = o[t][r];
        if (quad == 0) {
            ml[g * 32 + l15] = m_r;
            ml[g * 32 + 16 + l15] = l_r;
        }
    }
    __syncthreads();
    if (p == 0) {
        float m1 = ml[g * 32 + l15];
        float l1 = ml[g * 32 + 16 + l15];
        float M = fmaxf(m_r, m1);
        float w0 = exp2f(m_r - M);
        float w1 = exp2f(m1 - M);
        float L = w0 * l_r + w1 * l1;
        float inv = 1.0f / L;
        float* og = out + (size_t)(b * Sn + q0 + g * 16 + l15) * Hn;
        for (int t = 0; t < 8; ++t) {
            float4 st;
            float* mor = &mo[(size_t)(g * 128 + t * 16 + quad * 4) * 17 + l15];
            st.x = (w0 * o[t][0] + w1 * mor[0 * 17]) * inv;
            st.y = (w0 * o[t][1] + w1 * mor[1 * 17]) * inv;
            st.z = (w0 * o[t][2] + w1 * mor[2 * 17]) * inv;
            st.w = (w0 * o[t][3] + w1 * mor[3 * 17]) * inv;
            *(float4*)&og[t * 16 + quad * 4] = st;
        }
    }
}

extern "C" void kernel_launch(void* const* d_in, const int* in_sizes, int n_in,
                              void* d_out, int out_size, void* d_ws, size_t ws_size,
                              hipStream_t stream)
{
    const float* x  = (const float*)d_in[0];
    const float* Wk = (const float*)d_in[1];
    const float* Wq = (const float*)d_in[2];
    const float* Wv = (const float*)d_in[3];
    float* out = (float*)d_out;

    unsigned short* qbuf  = (unsigned short*)d_ws;                  // 4 MB
    unsigned short* kbuf  = qbuf + (size_t)Bn * Sn * Hn;            // 4 MB
    unsigned short* vbufT = kbuf + (size_t)Bn * Sn * Hn;            // 4 MB, [b][h][s]
    unsigned short* wb    = vbufT + (size_t)Bn * Sn * Hn;           // 0.75 MB, [q,k,v][h][E]

    prep_kernel<<<96, 256, 0, stream>>>(Wk, Wq, Wv, wb);
    proj_kernel<<<Bn * Sn / 32, 256, 0, stream>>>(x, wb, qbuf, kbuf, vbufT);
    attn_kernel<<<dim3(Sn / 32, Bn), 256, 0, stream>>>(qbuf, kbuf, vbufT, out);
}

// Round 6
// 213.460 us; speedup vs baseline: 1.0652x; 1.0652x over previous
//
#include <hip/hip_runtime.h>

typedef short bf16x8 __attribute__((ext_vector_type(8)));
typedef float f32x4 __attribute__((ext_vector_type(4)));

#define MFMA16(a, b, c) __builtin_amdgcn_mfma_f32_16x16x32_bf16(a, b, c, 0, 0, 0)

constexpr int Bn = 4, Sn = 4096, En = 1024, Hn = 128;
constexpr float CSCALE = 1.44269504089f * 0.03125f;   // log2(e) * E^-0.5

__device__ inline unsigned short f2bf(float f) {
    unsigned int u = __builtin_bit_cast(unsigned int, f);
    u += 0x7fff + ((u >> 16) & 1);   // RTN
    return (unsigned short)(u >> 16);
}

// pack 2 floats -> 2 bf16 (round-to-nearest-away): 2 adds + 1 v_perm
__device__ inline unsigned int pk2(float a, float b) {
    unsigned int ua = __builtin_bit_cast(unsigned int, a) + 0x8000u;
    unsigned int ub = __builtin_bit_cast(unsigned int, b) + 0x8000u;
    return __builtin_amdgcn_perm(ub, ua, 0x07060302u);
}

// async 16B/lane global->LDS: lds base must be wave-uniform; HW scatters lane*16
__device__ inline void gld16(const unsigned short* g, unsigned short* l) {
    __builtin_amdgcn_global_load_lds((const __attribute__((address_space(1))) void*)g,
                                     (__attribute__((address_space(3))) void*)l, 16, 0, 0);
}

// ---------------- QKV projection (R4 structure + cscale folded into q) ----------------
// 64x128 tiles: grid (BS/64, 3), block 256 (4 waves; wave tile 32x64).
// gy 0: q = (x Wq^T)*CSCALE   gy 1: k = x Wk^T   gy 2: vT = Wv x^T (A/B swapped)
__global__ __launch_bounds__(256, 2) void proj_kernel(
    const float* __restrict__ x,
    const float* __restrict__ Wk, const float* __restrict__ Wq, const float* __restrict__ Wv,
    unsigned short* __restrict__ qb, unsigned short* __restrict__ kb,
    unsigned short* __restrict__ vbT)
{
    __shared__ unsigned short xs[64][68];
    __shared__ unsigned short wsm[128][68];

    const int gy = blockIdx.y;
    const float* W = (gy == 0) ? Wq : (gy == 1) ? Wk : Wv;

    const int m0 = blockIdx.x * 64;
    const int tid = threadIdx.x;
    const int lane = tid & 63, wave = tid >> 6;
    const int l15 = lane & 15, quad = lane >> 4;
    const int wm = (wave & 1) * 32;
    const int wn = (wave >> 1) * 64;

    f32x4 acc[2][4] = {};

    float4 xp[4], wp[8];
    for (int p = 0; p < 4; ++p) {
        int i = p * 256 + tid, row = i >> 4, c = (i & 15) * 4;
        xp[p] = *(const float4*)&x[(size_t)(m0 + row) * En + c];
    }
    for (int p = 0; p < 8; ++p) {
        int i = p * 256 + tid, row = i >> 4, c = (i & 15) * 4;
        wp[p] = *(const float4*)&W[(size_t)row * En + c];
    }

    for (int kc = 0; kc < En / 64; ++kc) {
        for (int p = 0; p < 4; ++p) {
            int i = p * 256 + tid, row = i >> 4, c = (i & 15) * 4;
            uint2 w2 = { pk2(xp[p].x, xp[p].y), pk2(xp[p].z, xp[p].w) };
            *(uint2*)&xs[row][c] = w2;
        }
        for (int p = 0; p < 8; ++p) {
            int i = p * 256 + tid, row = i >> 4, c = (i & 15) * 4;
            uint2 w2 = { pk2(wp[p].x, wp[p].y), pk2(wp[p].z, wp[p].w) };
            *(uint2*)&wsm[row][c] = w2;
        }
        __syncthreads();
        if (kc + 1 < En / 64) {
            int k0 = (kc + 1) * 64;
            for (int p = 0; p < 4; ++p) {
                int i = p * 256 + tid, row = i >> 4, c = (i & 15) * 4;
                xp[p] = *(const float4*)&x[(size_t)(m0 + row) * En + k0 + c];
            }
            for (int p = 0; p < 8; ++p) {
                int i = p * 256 + tid, row = i >> 4, c = (i & 15) * 4;
                wp[p] = *(const float4*)&W[(size_t)row * En + k0 + c];
            }
        }
        if (gy != 2) {
            for (int kk = 0; kk < 2; ++kk) {
                bf16x8 af[2], bfr[4];
                for (int i = 0; i < 2; ++i) af[i]  = *(const bf16x8*)&xs[wm + i * 16 + l15][kk * 32 + quad * 8];
                for (int j = 0; j < 4; ++j) bfr[j] = *(const bf16x8*)&wsm[wn + j * 16 + l15][kk * 32 + quad * 8];
                for (int i = 0; i < 2; ++i)
                    for (int j = 0; j < 4; ++j)
                        acc[i][j] = MFMA16(af[i], bfr[j], acc[i][j]);
            }
        } else {
            for (int kk = 0; kk < 2; ++kk) {
                bf16x8 aw[4], bx[2];
                for (int j = 0; j < 4; ++j) aw[j] = *(const bf16x8*)&wsm[wn + j * 16 + l15][kk * 32 + quad * 8];
                for (int i = 0; i < 2; ++i) bx[i] = *(const bf16x8*)&xs[wm + i * 16 + l15][kk * 32 + quad * 8];
                for (int i = 0; i < 2; ++i)
                    for (int j = 0; j < 4; ++j)
                        acc[i][j] = MFMA16(aw[j], bx[i], acc[i][j]);
            }
        }
        __syncthreads();
    }

    if (gy != 2) {
        unsigned short* ob = (gy == 0) ? qb : kb;
        const float osc = (gy == 0) ? CSCALE : 1.0f;
        for (int i = 0; i < 2; ++i) {
            int rowb = m0 + wm + i * 16 + quad * 4;
            for (int j = 0; j < 4; ++j) {
                int col = wn + j * 16 + l15;
                for (int r = 0; r < 4; ++r)
                    ob[(size_t)(rowb + r) * Hn + col] = f2bf(acc[i][j][r] * osc);
            }
        }
    } else {
        for (int j = 0; j < 4; ++j) {
            int hb = wn + j * 16 + quad * 4;
            for (int i = 0; i < 2; ++i) {
                int sp = m0 + wm + i * 16 + l15;
                int bb = sp >> 12, ss = sp & 4095;
                for (int r = 0; r < 4; ++r)
                    vbT[((size_t)(bb * 128 + hb + r)) * Sn + ss] = f2bf(acc[i][j][r]);
            }
        }
    }
}

// ---------------- flash causal attention: async staging, BK=32, 2-way k-split ----------------
// grid (S/32, B), block 256 = 4 waves = 2 pairs (p = k-split, g = q-row group).
// K/V tiles double-buffered, loaded via global_load_lds into XOR-swizzled unpadded LDS.
// ONE barrier per k-tile. S^T = K Q^T orientation; q pre-scaled by CSCALE in proj.
__global__ __launch_bounds__(256, 2) void attn_kernel(
    const unsigned short* __restrict__ qb, const unsigned short* __restrict__ kb,
    const unsigned short* __restrict__ vbT, float* __restrict__ out)
{
    // [p][buf] 16 KB blocks: K tile 8 KB (32 keys x 16 chunks) + V^T 8 KB (128 h x 4 chunks)
    __shared__ __align__(16) unsigned char smem[70144];
    unsigned short* psb = (unsigned short*)(smem + 65536);   // [p][32 q][36]

    const int b = blockIdx.y;
    const int qt = (int)gridDim.x - 1 - (int)blockIdx.x;     // longest blocks first
    const int q0 = qt * 32;
    const int tid = threadIdx.x;
    const int lane = tid & 63, wave = tid >> 6;
    const int l15 = lane & 15, quad = lane >> 4;
    const int g = wave & 1;        // q-row group
    const int p = wave >> 1;       // k-split

    const unsigned short* qg = qb + (size_t)(b * Sn + q0) * Hn;
    bf16x8 qf[4];
    {
        int qrow = g * 16 + l15;
        for (int f = 0; f < 4; ++f)
            qf[f] = *(const bf16x8*)&qg[qrow * Hn + f * 32 + quad * 8];
    }

    f32x4 o[8] = {};
    float m_r = -INFINITY, l_r = 0.f;

    const int nkt = qt + 1;          // 32-key tiles
    const int ni = (nkt + 1) >> 1;

    const unsigned short* kg = kb + (size_t)b * Sn * Hn;
    const unsigned short* vg = vbT + (size_t)b * 128 * Sn;

    unsigned short* psrow = &psb[(p * 32 + g * 16 + l15) * 36];

    // issue one K/V tile (kt) into buffer c: 4 K-insts + 4 V-insts per wave, 1 KB each
    auto issue = [&](int kt, int c) {
        char* base = (char*)smem + (p * 2 + c) * 16384;
        int kt0 = kt * 32;
        for (int j = 0; j < 4; ++j) {
            int seg = (g * 4 + j) * 1024;
            // K: flat dst byte = seg + lane*16 -> key = dst>>8, chunk = (dst>>4)&15
            int dk = seg + lane * 16;
            int key = dk >> 8, ch = (dk >> 4) & 15;
            gld16(kg + (size_t)(kt0 + key) * Hn + ((ch ^ (key & 7)) << 3),
                  (unsigned short*)(base + seg));
            // V^T: dst -> h = dst>>6, chunk = (dst>>4)&3
            int h = dk >> 6, cc = (dk >> 4) & 3;
            gld16(vg + (size_t)h * Sn + kt0 + ((cc ^ (h & 3)) << 3),
                  (unsigned short*)(base + 8192 + seg));
        }
    };

    if (p < nkt) issue(p, 0);

    for (int it = 0; it < ni; ++it) {
        const int kt = 2 * it + p;
        __syncthreads();                 // buf[it&1] landed; buf[(it+1)&1] free
        if (kt + 2 < nkt) issue(kt + 2, (it + 1) & 1);
        if (kt < nkt) {
            unsigned short* kbase = (unsigned short*)((char*)smem + (p * 2 + (it & 1)) * 16384);
            unsigned short* vbase = kbase + 4096;

            // S^T: A = K (m=key), B = Q (n=q). u[nt][r]: key = kt*32+nt*16+quad*4+r, q = l15
            float u[2][4];
            for (int nt = 0; nt < 2; ++nt) {
                f32x4 s = {};
                for (int kk = 0; kk < 4; ++kk) {
                    int ch = (kk * 4 + quad) ^ (l15 & 7);
                    bf16x8 kf = *(const bf16x8*)&kbase[(nt * 16 + l15) * 128 + ch * 8];
                    s = MFMA16(kf, qf[kk], s);
                }
                for (int r = 0; r < 4; ++r) u[nt][r] = s[r];
            }
            if (kt == nkt - 1) {   // diagonal tile: kt*32 == q0
                int qq = g * 16 + l15;
                for (int nt = 0; nt < 2; ++nt)
                    for (int r = 0; r < 4; ++r)
                        if (nt * 16 + quad * 4 + r > qq) u[nt][r] = -INFINITY;
            }
            // per-lane online softmax (log2 domain; cscale pre-folded into q)
            float mx = -INFINITY;
            for (int nt = 0; nt < 2; ++nt)
                for (int r = 0; r < 4; ++r) mx = fmaxf(mx, u[nt][r]);
            mx = fmaxf(mx, __shfl_xor(mx, 16));
            mx = fmaxf(mx, __shfl_xor(mx, 32));
            float mn = fmaxf(m_r, mx);
            float alpha = exp2f(m_r - mn);
            m_r = mn;
            float sum = 0.f;
            for (int nt = 0; nt < 2; ++nt)
                for (int r = 0; r < 4; ++r) {
                    float pv = exp2f(u[nt][r] - mn);
                    u[nt][r] = pv;
                    sum += pv;
                }
            sum += __shfl_xor(sum, 16);
            sum += __shfl_xor(sum, 32);
            l_r = l_r * alpha + sum;

            // P -> LDS [q][key] (same-wave strip, no barrier)
            for (int nt = 0; nt < 2; ++nt) {
                uint2 w2 = { pk2(u[nt][0], u[nt][1]), pk2(u[nt][2], u[nt][3]) };
                *(uint2*)&psrow[nt * 16 + quad * 4] = w2;
            }
            for (int t = 0; t < 8; ++t) o[t] *= alpha;

            // O^T += V^T P^T : vf from swizzled vt, pf from ps
            bf16x8 pf = *(const bf16x8*)&psrow[quad * 8];
            for (int t = 0; t < 8; ++t) {
                int hh = t * 16 + l15;
                bf16x8 vf = *(const bf16x8*)&vbase[hh * 32 + ((quad ^ (l15 & 3)) << 3)];
                o[t] = MFMA16(vf, pf, o[t]);
            }
        }
    }
    __syncthreads();

    // ---- merge the two k-split partials (LDS overlay) ----
    float* mo = (float*)smem;                    // [2][128][17] f32 (17408 B)
    float* ml = (float*)(smem + 20480);          // [2][{m,l}][16] f32
    if (p == 1) {
        for (int t = 0; t < 8; ++t)
            for (int r = 0; r < 4; ++r)
                mo[(size_t)(g * 128 + t * 16 + quad * 4 + r) * 17 + l15] = o[t][r];
        if (quad == 0) {
            ml[g * 32 + l15] = m_r;
            ml[g * 32 + 16 + l15] = l_r;
        }
    }
    __syncthreads();
    if (p == 0) {
        float m1 = ml[g * 32 + l15];
        float l1 = ml[g * 32 + 16 + l15];
        float M = fmaxf(m_r, m1);
        float w0 = exp2f(m_r - M);
        float w1 = exp2f(m1 - M);
        float L = w0 * l_r + w1 * l1;
        float inv = 1.0f / L;
        float* og = out + (size_t)(b * Sn + q0 + g * 16 + l15) * Hn;
        for (int t = 0; t < 8; ++t) {
            float4 st;
            float* mor = &mo[(size_t)(g * 128 + t * 16 + quad * 4) * 17 + l15];
            st.x = (w0 * o[t][0] + w1 * mor[0 * 17]) * inv;
            st.y = (w0 * o[t][1] + w1 * mor[1 * 17]) * inv;
            st.z = (w0 * o[t][2] + w1 * mor[2 * 17]) * inv;
            st.w = (w0 * o[t][3] + w1 * mor[3 * 17]) * inv;
            *(float4*)&og[t * 16 + quad * 4] = st;
        }
    }
}

extern "C" void kernel_launch(void* const* d_in, const int* in_sizes, int n_in,
                              void* d_out, int out_size, void* d_ws, size_t ws_size,
                              hipStream_t stream)
{
    const float* x  = (const float*)d_in[0];
    const float* Wk = (const float*)d_in[1];
    const float* Wq = (const float*)d_in[2];
    const float* Wv = (const float*)d_in[3];
    float* out = (float*)d_out;

    unsigned short* qbuf  = (unsigned short*)d_ws;                  // 4 MB (pre-scaled by CSCALE)
    unsigned short* kbuf  = qbuf + (size_t)Bn * Sn * Hn;            // 4 MB
    unsigned short* vbufT = kbuf + (size_t)Bn * Sn * Hn;            // 4 MB, [b][h][s]

    proj_kernel<<<dim3(Bn * Sn / 64, 3), 256, 0, stream>>>(x, Wk, Wq, Wv, qbuf, kbuf, vbufT);
    attn_kernel<<<dim3(Sn / 32, Bn), 256, 0, stream>>>(qbuf, kbuf, vbufT, out);
}